// Round 2
// baseline (3312.896 us; speedup 1.0000x reference)
//
#include <hip/hip_runtime.h>

#define Bn 256
#define Tn 2048
#define Dn 40
#define Hn 128
#define Cn 35

typedef _Float16 h2 __attribute__((ext_vector_type(2)));

__device__ __forceinline__ float fdot2f(h2 a, h2 b, float c) {
#if __has_builtin(__builtin_amdgcn_fdot2)
  return __builtin_amdgcn_fdot2(a, b, c, false);
#else
  return c + (float)(a[0]) * (float)(b[0]) + (float)(a[1]) * (float)(b[1]);
#endif
}

__device__ __forceinline__ h2 pk2(float a, float b) {
  h2 r; r[0] = (_Float16)a; r[1] = (_Float16)b; return r;
}

// broadcast pair from lane `l` of a wave-resident int (readlane -> SGPR)
__device__ __forceinline__ h2 bcast(int v, int l) {
  return __builtin_bit_cast(h2, __builtin_amdgcn_readlane(v, l));
}

__device__ __forceinline__ float rcpf_(float x) {
#if __has_builtin(__builtin_amdgcn_rcpf)
  return __builtin_amdgcn_rcpf(x);
#else
  return 1.f / x;
#endif
}

__device__ __forceinline__ float sigm(float v) {
  v = fmaxf(fminf(v, 60.f), -60.f);
  return rcpf_(1.f + __expf(-v));
}

__device__ __forceinline__ float tanha(float v) {
  v = fmaxf(fminf(v, 15.f), -15.f);
  const float e = __expf(2.f * v);
  return (e - 1.f) * rcpf_(e + 1.f);
}

struct H8u { h2 p[4]; };
__device__ __forceinline__ H8u ld8(const h2* base, int idx4) {
  const uint4 u = reinterpret_cast<const uint4*>(base)[idx4];
  H8u r;
  r.p[0] = __builtin_bit_cast(h2, u.x);
  r.p[1] = __builtin_bit_cast(h2, u.y);
  r.p[2] = __builtin_bit_cast(h2, u.z);
  r.p[3] = __builtin_bit_cast(h2, u.w);
  return r;
}

// One workgroup per batch element; 512 threads; thread owns gate column `tid`
// of BOTH layers. 212 packed-f16-pair weights register-resident (cap 256 via
// amdgpu_waves_per_eu(2,2) -- launch_bounds(512,2) gave cap 128 + spills).
// Step = { U: cell updates + x staging | barrier | G: g0(t+1) AND g1(t) as one
// dot2 stream | barrier }. h operands delivered via v_readlane->SGPR (VALU)
// instead of broadcast LDS b128 reads (round-1 bottleneck: LDS return bus,
// ~3400 cy/step). One readlane of h0 feeds both w0h and w1x dot2s.
__global__ __launch_bounds__(512)
__attribute__((amdgpu_waves_per_eu(2, 2)))
void lstm2_fused(
    const float* __restrict__ x,
    const int*   __restrict__ length,
    const float* __restrict__ Wih0, const float* __restrict__ Whh0,
    const float* __restrict__ bih0, const float* __restrict__ bhh0,
    const float* __restrict__ Wih1, const float* __restrict__ Whh1,
    const float* __restrict__ bih1, const float* __restrict__ bhh1,
    const float* __restrict__ gam,  const float* __restrict__ bet,
    const float* __restrict__ fcw,  const float* __restrict__ fcb,
    float* __restrict__ out)
{
  __shared__ __align__(16) h2 s_x[16 * 20];  // 16-step x chunk, 20 pairs/row (80B, 16B-aligned)
  __shared__ __align__(16) h2 s_h0[64];
  __shared__ __align__(16) h2 s_h1[64];
  __shared__ float s_g0[512];
  __shared__ float s_g1[512];
  __shared__ float s_h1f[128];
  __shared__ float s_hn[128];

  const int tid  = threadIdx.x;
  const int lane = tid & 63;
  const int b    = blockIdx.x;
  const int len  = length[b];  // 1..2048

  // ---- register-resident weights (packed f16 pairs) ----
  h2 w0x[20]; h2 w0h[64]; h2 w1x[64]; h2 w1h[64];
  {
    const float* p = Wih0 + tid * Dn;
#pragma unroll
    for (int j = 0; j < 20; ++j) w0x[j] = pk2(p[2 * j], p[2 * j + 1]);
  }
  {
    const float* p = Whh0 + tid * Hn;
#pragma unroll
    for (int j = 0; j < 64; ++j) w0h[j] = pk2(p[2 * j], p[2 * j + 1]);
  }
  {
    const float* p = Wih1 + tid * Hn;
#pragma unroll
    for (int j = 0; j < 64; ++j) w1x[j] = pk2(p[2 * j], p[2 * j + 1]);
  }
  {
    const float* p = Whh1 + tid * Hn;
#pragma unroll
    for (int j = 0; j < 64; ++j) w1h[j] = pk2(p[2 * j], p[2 * j + 1]);
  }
  const float bias0 = bih0[tid] + bhh0[tid];
  const float bias1 = bih1[tid] + bhh1[tid];

  float c0 = 0.f;  // threads 0..127   : L0 cell
  float c1 = 0.f;  // threads 128..255 : L1 cell

  if (tid < 64) {
    ((int*)s_h0)[tid] = 0;
    ((int*)s_h1)[tid] = 0;
  }
  // stage x chunk 0 (rows 0..15)
  if (tid < 160) {
    const int r = tid / 10, q = tid - r * 10;
    const float4 v = *reinterpret_cast<const float4*>(
        x + ((size_t)b * Tn + (size_t)r) * Dn + 4 * q);
    s_x[r * 20 + 2 * q]     = pk2(v.x, v.y);
    s_x[r * 20 + 2 * q + 1] = pk2(v.z, v.w);
  }
  __syncthreads();

  // prologue: g0(0) = bias0 + x(0).w0x   (h0(-1)=0)
  {
    float a0 = bias0, a1 = 0.f;
    const h2* xr = s_x;
#pragma unroll
    for (int j = 0; j < 5; ++j) {
      const H8u v = ld8(xr, j);
      a0 = fdot2f(v.p[0], w0x[4 * j + 0], a0);
      a1 = fdot2f(v.p[1], w0x[4 * j + 1], a1);
      a0 = fdot2f(v.p[2], w0x[4 * j + 2], a0);
      a1 = fdot2f(v.p[3], w0x[4 * j + 3], a1);
    }
    s_g0[tid] = a0 + a1;
  }
  __syncthreads();

  float4 xstage;  // pending x prefetch (threads 256..415, every 16 steps)

#pragma unroll 1
  for (int t = 0; t < len; ++t) {
    // ---- U phase: cell updates + x stage ----
    if (tid < 128) {
      const float gi = s_g0[tid], gf = s_g0[Hn + tid];
      const float gg = s_g0[2 * Hn + tid], go = s_g0[3 * Hn + tid];
      c0 = sigm(gf) * c0 + sigm(gi) * tanha(gg);
      reinterpret_cast<_Float16*>(s_h0)[tid] = (_Float16)(sigm(go) * tanha(c0));
    } else if (tid < 256) {
      if (t > 0) {
        const int u = tid - 128;
        const float gi = s_g1[u], gf = s_g1[Hn + u];
        const float gg = s_g1[2 * Hn + u], go = s_g1[3 * Hn + u];
        c1 = sigm(gf) * c1 + sigm(gi) * tanha(gg);
        reinterpret_cast<_Float16*>(s_h1)[u] = (_Float16)(sigm(go) * tanha(c1));
      }
    } else if (tid < 416) {
      const int ph = t & 15;
      if (ph == 14) {
        // prefetch chunk starting at T0 = t+2 (latency hidden under G(t))
        const int u = tid - 256, r = u / 10, q = u - r * 10;
        int tr = t + 2 + r; if (tr > Tn - 1) tr = Tn - 1;
        xstage = *reinterpret_cast<const float4*>(
            x + ((size_t)b * Tn + (size_t)tr) * Dn + 4 * q);
      } else if (ph == 15) {
        // commit: rows t+1 .. t+16 ; G(t) reads row (t+1)&15 == 0 (new chunk)
        const int u = tid - 256, r = u / 10, q = u - r * 10;
        s_x[r * 20 + 2 * q]     = pk2(xstage.x, xstage.y);
        s_x[r * 20 + 2 * q + 1] = pk2(xstage.z, xstage.w);
      }
    }
    __syncthreads();

    // ---- G phase: g0(t+1) and g1(t) as one interleaved dot2 stream ----
    const int vh0 = ((const int*)s_h0)[lane];  // pair `lane` of h0(t)
    const int vh1 = ((const int*)s_h1)[lane];  // pair `lane` of h1(t-1)

    float a0 = bias0, a1 = 0.f;  // g0(t+1)
    float b0 = bias1, b1 = 0.f;  // g1(t)
    {
      const h2* xr = s_x + ((t + 1) & 15) * 20;
#pragma unroll
      for (int j = 0; j < 5; ++j) {
        const H8u v = ld8(xr, j);
        a0 = fdot2f(v.p[0], w0x[4 * j + 0], a0);
        a1 = fdot2f(v.p[1], w0x[4 * j + 1], a1);
        a0 = fdot2f(v.p[2], w0x[4 * j + 2], a0);
        a1 = fdot2f(v.p[3], w0x[4 * j + 3], a1);
      }
    }
#pragma unroll
    for (int j = 0; j < 64; j += 2) {
      const h2 p0 = bcast(vh0, j);
      const h2 p1 = bcast(vh0, j + 1);
      a0 = fdot2f(p0, w0h[j],     a0);
      b0 = fdot2f(p0, w1x[j],     b0);
      a1 = fdot2f(p1, w0h[j + 1], a1);
      b1 = fdot2f(p1, w1x[j + 1], b1);
    }
#pragma unroll
    for (int j = 0; j < 64; j += 2) {
      const h2 p0 = bcast(vh1, j);
      const h2 p1 = bcast(vh1, j + 1);
      b0 = fdot2f(p0, w1h[j],     b0);
      b1 = fdot2f(p1, w1h[j + 1], b1);
    }
    s_g0[tid] = a0 + a1;
    s_g1[tid] = b0 + b1;
    __syncthreads();
  }

  // ---- epilogue: final h1 update at t = len-1 (fp32) ----
  if (tid >= 128 && tid < 256) {
    const int u = tid - 128;
    const float gi = s_g1[u], gf = s_g1[Hn + u];
    const float gg = s_g1[2 * Hn + u], go = s_g1[3 * Hn + u];
    c1 = sigm(gf) * c1 + sigm(gi) * tanha(gg);
    s_h1f[u] = sigm(go) * tanha(c1);
  }
  __syncthreads();

  // ---- LayerNorm over H on wave 0 ----
  if (tid < 64) {
    const float a = s_h1f[tid], d = s_h1f[64 + tid];
    float s = a + d, q = a * a + d * d;
#pragma unroll
    for (int m = 32; m >= 1; m >>= 1) {
      s += __shfl_xor(s, m, 64);
      q += __shfl_xor(q, m, 64);
    }
    const float mu = s * (1.f / 128.f);
    float var = q * (1.f / 128.f) - mu * mu;
    var = fmaxf(var, 0.f);
    const float rstd = rsqrtf(var + 1e-5f);
    s_hn[tid]      = (a - mu) * rstd * gam[tid]      + bet[tid];
    s_hn[64 + tid] = (d - mu) * rstd * gam[64 + tid] + bet[64 + tid];
  }
  __syncthreads();

  // ---- FC head ----
  if (tid < Cn) {
    float acc = fcb[tid];
    const float* wp = fcw + tid * Hn;
#pragma unroll 4
    for (int k = 0; k < Hn; ++k) acc += s_hn[k] * wp[k];
    out[(size_t)b * Cn + tid] = acc;
  }
}

extern "C" void kernel_launch(void* const* d_in, const int* in_sizes, int n_in,
                              void* d_out, int out_size, void* d_ws, size_t ws_size,
                              hipStream_t stream) {
  (void)in_sizes; (void)n_in; (void)d_ws; (void)ws_size; (void)out_size;
  lstm2_fused<<<dim3(Bn), dim3(512), 0, stream>>>(
      (const float*)d_in[0],  (const int*)d_in[1],
      (const float*)d_in[2],  (const float*)d_in[3],
      (const float*)d_in[4],  (const float*)d_in[5],
      (const float*)d_in[6],  (const float*)d_in[7],
      (const float*)d_in[8],  (const float*)d_in[9],
      (const float*)d_in[10], (const float*)d_in[11],
      (const float*)d_in[12], (const float*)d_in[13],
      (float*)d_out);
}